// Round 5
// baseline (584.377 us; speedup 1.0000x reference)
//
#include <hip/hip_runtime.h>
#include <hip/hip_bf16.h>
#include <cstdint>
#include <cstddef>

// Problem constants
#define HIDDEN   768
#define HID_F    3072
#define PART     192
#define SHARED_F 576
#define NEXP     6
#define BATCH    32
#define SEQ      1024
#define M_TOK    (BATCH * SEQ)   // 32768

typedef __bf16 bf16;
typedef __attribute__((ext_vector_type(8))) __bf16 bf16x8;
typedef __attribute__((ext_vector_type(4))) __bf16 bf16x4;
typedef __attribute__((ext_vector_type(4))) float  f32x4;

// ---- async global -> LDS copy, 16B per lane -----------------------------
__device__ __forceinline__ void gl2lds16(const void* g, void* l) {
    __builtin_amdgcn_global_load_lds(
        (const __attribute__((address_space(1))) void*)g,
        (__attribute__((address_space(3))) void*)l,
        16, 0, 0);
}

__device__ __forceinline__ f32x4 mfma16(bf16x8 a, bf16x8 b, f32x4 c) {
    return __builtin_amdgcn_mfma_f32_16x16x32_bf16(a, b, c, 0, 0, 0);
}

// compiler fence + raw barrier (no vmcnt/lgkm drain like __syncthreads)
#define CFENCE() asm volatile("" ::: "memory")
__device__ __forceinline__ void barrier_raw() {
    CFENCE();
    __builtin_amdgcn_s_barrier();
    CFENCE();
}

// Exact-GELU via Abramowitz-Stegun 7.1.26 rational erf (|eps| <= 1.5e-7).
__device__ __forceinline__ float gelu_fast(float x) {
    float xs = x * 0.70710678118654752f;       // x / sqrt(2)
    float ax = __builtin_fabsf(xs);
    float t  = __builtin_amdgcn_rcpf(1.0f + 0.3275911f * ax);
    float p  = t * (0.254829592f +
               t * (-0.284496736f +
               t * (1.421413741f +
               t * (-1.453152027f +
               t * 1.061405429f))));
    float e  = __expf(-xs * xs);
    float er = 1.0f - p * e;                   // erf(|xs|)
    er = (xs < 0.0f) ? -er : er;
    return 0.5f * x * (1.0f + er);
}

// ---- prep: fp32 -> bf16 vectorized convert ------------------------------
__global__ __launch_bounds__(256) void cvt_f32_bf16(
        const float4* __restrict__ src, bf16x4* __restrict__ dst, int n4) {
    int i      = blockIdx.x * 256 + threadIdx.x;
    int stride = gridDim.x * 256;
    for (; i < n4; i += stride) {
        float4 v = src[i];
        bf16x4 o = { (__bf16)v.x, (__bf16)v.y, (__bf16)v.z, (__bf16)v.w };
        dst[i] = o;
    }
}

// ---- prep: tiled transpose fp32[K][N] -> bf16[N][K] ---------------------
__global__ __launch_bounds__(256) void transpose_cvt(
        const float* __restrict__ src, bf16* __restrict__ dst, int K, int N) {
    __shared__ float t[32][33];
    const int n0 = blockIdx.x * 32, k0 = blockIdx.y * 32;
    const int tx = threadIdx.x & 31, ty = threadIdx.x >> 5;  // ty in 0..7
#pragma unroll
    for (int p = 0; p < 4; ++p) {
        int r = ty + p * 8;
        t[r][tx] = src[(size_t)(k0 + r) * N + n0 + tx];
    }
    __syncthreads();
#pragma unroll
    for (int p = 0; p < 4; ++p) {
        int rn = ty + p * 8;
        dst[(size_t)(n0 + rn) * K + k0 + tx] = (bf16)t[tx][rn];
    }
}

// ---- prep: Wcat[e][n][k] = (n<576 ? W2[k][n] : We[e][k][n-576]) as bf16 --
__global__ __launch_bounds__(256) void build_wcat(
        const float* __restrict__ W2, const float* __restrict__ We,
        bf16* __restrict__ Wcat) {
    __shared__ float t[32][33];
    const int e  = blockIdx.z;
    const int n0 = blockIdx.x * 32;
    const int k0 = blockIdx.y * 32;
    const int tx = threadIdx.x & 31, ty = threadIdx.x >> 5;
    const float* src;
    int ld, c;
    if (n0 < SHARED_F) { src = W2; ld = SHARED_F; c = n0 + tx; }
    else { src = We + (size_t)e * HID_F * PART; ld = PART; c = n0 + tx - SHARED_F; }
#pragma unroll
    for (int p = 0; p < 4; ++p) {
        int r = ty + p * 8;
        t[r][tx] = src[(size_t)(k0 + r) * ld + c];
    }
    __syncthreads();
    bf16* dst = Wcat + (size_t)e * HIDDEN * HID_F;
#pragma unroll
    for (int p = 0; p < 4; ++p) {
        int rn = ty + p * 8;
        dst[(size_t)(n0 + rn) * HID_F + k0 + tx] = (bf16)t[tx][rn];
    }
}

// ==========================================================================
// 256x256-tile, BK=64, 8-wave (2M x 4N): register-pipelined 4-phase K-loop
// with PER-PHASE barrier pairs (m201 phase-locking) + counted vmcnt.
//
// Phase shape: { STAGE (pre-bar) [; vmcnt] ; BAR ; ds_reads (for FUTURE
// phases) ; 16 MFMA (setprio-wrapped) ; BAR }.  Reads feed phases >=1
// ahead, so the compiler's counted lgkm waits leave them draining under
// the MFMA cluster; barrier pairs keep all 8 waves phase-locked so
// ds_read / gload / MFMA interleave every phase (m196's lever).
//
// Stages per tile t: p0: A1(t+1)->bo  p1: B1(t+1)->bo
//                    p2: A0(t+2)->b   p3: B0(t+2)->b
// Reads  per tile t: p0: bfr1(t)[4]   p1: afr1(t)[8]
//                    p3: afr0(t+1)[8] + bfr0(t+1)[4]  (from bo)
// MFMA   per tile t: p0: q00(afr0,bfr0)  p1: q01(afr0,bfr1)
//                    p2: q10(afr1,bfr0)  p3: q11(afr1,bfr1)
//
// Race-free read guarantee (all-waves): a slot is readable only after an
// {vmcnt retiring it ; s_barrier} pair.  vmcnt(4) before p0-bar retires
// {A1(t),B1(t),A0(t+1)} (queue=10 at that point); vmcnt(4) before p2-bar
// retires {B0(t+1),A1(t+1)} (queue=8).  Every read above follows its
// guarantee barrier.  Waited loads are 2-3 phases old (>= HBM latency).
// 3-4 half-tiles in flight; never vmcnt(0).  No manual lgkmcnt, no
// sched_barrier (m141/m97: compiler's counted waits are near-optimal).
// Tail: stage targets clamped to same-parity tiles (same slots, dead
// data) so vmcnt arithmetic stays exact; final p3 reads are dead.
// LDS chunk-XOR swizzle on both sides (global source + ds_read).
// ==========================================================================

#define STAGE_A(kt, hm, bb) do {                                          \
    const bf16* g_ = gA + (size_t)((hm) * 128) * LDA + (kt) * 64;         \
    bf16* l_ = lA + ((bb) * 2 + (hm)) * 8192;                             \
    gl2lds16(g_, l_);                                                     \
    gl2lds16(g_ + (size_t)64 * LDA, l_ + 4096);                           \
} while (0)

#define STAGE_B(kt, hm, bb) do {                                          \
    const bf16* g_ = gB + (size_t)((hm) * 128) * LDB + (kt) * 64;         \
    bf16* l_ = lB + ((bb) * 2 + (hm)) * 8192;                             \
    gl2lds16(g_, l_);                                                     \
    gl2lds16(g_ + (size_t)64 * LDB, l_ + 4096);                           \
} while (0)

#define RD_A(dst, qm, bb) do {                                            \
    const bf16* ab_ = fA + ((bb) * 2 + (qm)) * 8192;                      \
    _Pragma("unroll")                                                     \
    for (int mi = 0; mi < 4; ++mi) {                                      \
        dst[mi][0] = *(const bf16x8*)(ab_ + mi * 1024 + pca0);            \
        dst[mi][1] = *(const bf16x8*)(ab_ + mi * 1024 + pca1);            \
    }                                                                     \
} while (0)

#define RD_B(dst, qn, bb) do {                                            \
    const bf16* bb_ = fB + ((bb) * 2 + (qn)) * 8192;                      \
    _Pragma("unroll")                                                     \
    for (int nj = 0; nj < 2; ++nj) {                                      \
        dst[nj][0] = *(const bf16x8*)(bb_ + nj * 1024 + pcb0);            \
        dst[nj][1] = *(const bf16x8*)(bb_ + nj * 1024 + pcb1);            \
    }                                                                     \
} while (0)

#define MFMA16(A_, B_, qm, qn) do {                                       \
    __builtin_amdgcn_s_setprio(1);                                        \
    _Pragma("unroll")                                                     \
    for (int mi = 0; mi < 4; ++mi)                                        \
        _Pragma("unroll")                                                 \
        for (int nj = 0; nj < 2; ++nj) {                                  \
            acc[(qm)*4+mi][(qn)*2+nj] =                                   \
                mfma16(A_[mi][0], B_[nj][0], acc[(qm)*4+mi][(qn)*2+nj]);  \
            acc[(qm)*4+mi][(qn)*2+nj] =                                   \
                mfma16(A_[mi][1], B_[nj][1], acc[(qm)*4+mi][(qn)*2+nj]);  \
        }                                                                 \
    __builtin_amdgcn_s_setprio(0);                                        \
} while (0)

// one K-tile; b/bo are literal 0/1 (compile-time LDS buffer parity)
#define TILE(t, b, bo) do {                                               \
    const int tp1_ = ((t) + 1 < NT) ? (t) + 1 : (t) - 1;                  \
    const int tp2_ = ((t) + 2 < NT) ? (t) + 2 : (t);                      \
    /* -- p0: stage A1(t+1); vmcnt; BAR; rd bfr1(t); q00 ------------- */ \
    STAGE_A(tp1_, 1, bo);                                                 \
    asm volatile("s_waitcnt vmcnt(4)" ::: "memory");                      \
    barrier_raw();                                                        \
    RD_B(bfr1, 1, b);                                                     \
    MFMA16(afr0, bfr0, 0, 0);                                             \
    barrier_raw();                                                        \
    /* -- p1: stage B1(t+1); BAR; rd afr1(t); q01 -------------------- */ \
    STAGE_B(tp1_, 1, bo);                                                 \
    barrier_raw();                                                        \
    RD_A(afr1, 1, b);                                                     \
    MFMA16(afr0, bfr1, 0, 1);                                             \
    barrier_raw();                                                        \
    /* -- p2: stage A0(t+2); vmcnt; BAR; q10 ------------------------- */ \
    STAGE_A(tp2_, 0, b);                                                  \
    asm volatile("s_waitcnt vmcnt(4)" ::: "memory");                      \
    barrier_raw();                                                        \
    MFMA16(afr1, bfr0, 1, 0);                                             \
    barrier_raw();                                                        \
    /* -- p3: stage B0(t+2); BAR; rd afr0/bfr0(t+1); q11 ------------- */ \
    STAGE_B(tp2_, 0, b);                                                  \
    barrier_raw();                                                        \
    RD_A(afr0, 0, bo);                                                    \
    RD_B(bfr0, 0, bo);                                                    \
    MFMA16(afr1, bfr1, 1, 1);                                             \
    barrier_raw();                                                        \
} while (0)

template<bool IS_FC1>
__global__ __launch_bounds__(512, 2) void fc_8ph(
        const bf16*  __restrict__ A,      // fc1: hb[32768][768]; fc2: H[32768][3072]
        const bf16*  __restrict__ Bmat,   // fc1: W1t[3072][768]; fc2: Wcat[6][768][3072]
        const float* __restrict__ bias1,  // fc1: b1[3072];       fc2: b2[576]
        const float* __restrict__ bias2,  // fc2: be[6][192]
        const int*   __restrict__ idx,    // fc2: [32]
        void*        __restrict__ Outv) { // fc1: bf16 H; fc2: f32 Out
    constexpr int LDA     = IS_FC1 ? HIDDEN : HID_F;
    constexpr int LDB     = LDA;
    constexpr int NT      = LDA / 64;                       // 12 / 48
    constexpr int NTILE_N = IS_FC1 ? (HID_F / 256) : (HIDDEN / 256); // 12 / 3
    constexpr int LDOUT   = IS_FC1 ? HID_F : HIDDEN;

    __shared__ alignas(16) bf16 Abuf[2 * 2 * 128 * 64];   // 64 KiB
    __shared__ alignas(16) bf16 Bbuf[2 * 2 * 128 * 64];   // 64 KiB

    const int tid  = threadIdx.x;
    const int wave = tid >> 6, lane = tid & 63;
    const int wm = wave >> 2, wn = wave & 3;              // 2M x 4N waves
    const int lrow = lane & 15, lk8 = (lane >> 4) & 3;

    // XCD-gather swizzle: 16 m-tiles per XCD, all n-tiles of an m-tile on one XCD
    const int L   = blockIdx.x;
    const int xcd = L & 7;
    const int j   = L >> 3;
    const int jm  = j / NTILE_N;
    const int mt  = xcd * 16 + jm;
    const int nt  = j - jm * NTILE_N;
    const int m0  = mt * 256;
    const int n0  = nt * 256;

    const bf16* Bt;
    int e = 0;
    if constexpr (IS_FC1) {
        Bt = Bmat;
    } else {
        e = idx[mt >> 2];                 // 4 m-tiles (256 rows) per batch elem
        e = e < 0 ? 0 : (e > NEXP - 1 ? NEXP - 1 : e);
        Bt = Bmat + (size_t)e * HIDDEN * HID_F;
    }

    // staging geometry: row = tid>>3; phys chunk = tid&7;
    // logical chunk = phys ^ (row&7)
    const int srow = tid >> 3;                       // 0..63
    const int lch  = (tid & 7) ^ (srow & 7);
    const bf16* gA = A  + (size_t)(m0 + srow) * LDA + lch * 8;
    const bf16* gB = Bt + (size_t)(n0 + srow) * LDB + lch * 8;
    bf16* lA = Abuf + wave * 512;                    // wave-uniform LDS base
    bf16* lB = Bbuf + wave * 512;

    // fragment-read geometry
    const int rA = wm * 64 + lrow;                   // row within 128-row half
    const int rB = wn * 32 + lrow;
    const int pca0 = ((0 + lk8) ^ (rA & 7)) * 8;     // phys-elem offset, ks=0
    const int pca1 = ((4 + lk8) ^ (rA & 7)) * 8;     // ks=1
    const int pcb0 = ((0 + lk8) ^ (rB & 7)) * 8;
    const int pcb1 = ((4 + lk8) ^ (rB & 7)) * 8;
    const bf16* fA = Abuf + rA * 64;
    const bf16* fB = Bbuf + rB * 64;

    f32x4 acc[8][4] = {};
    bf16x8 afr0[4][2], afr1[4][2], bfr0[2][2], bfr1[2][2];

    // prologue: stage A0(0),B0(0) then [A1(0),B1(0),A0(1),B0(1)] (12 ops);
    // vmcnt(8) retires A0(0),B0(0); barrier = guarantee point; read tile0's
    // afr0/bfr0. Queue entering the loop: [A1(0),B1(0),A0(1),B0(1)] = 8 ops
    // (exact steady-state pattern).
    STAGE_A(0, 0, 0); STAGE_B(0, 0, 0);
    STAGE_A(0, 1, 0); STAGE_B(0, 1, 0);
    STAGE_A(1, 0, 1); STAGE_B(1, 0, 1);
    asm volatile("s_waitcnt vmcnt(8)" ::: "memory");
    barrier_raw();
    RD_A(afr0, 0, 0);
    RD_B(bfr0, 0, 0);

#pragma unroll 1
    for (int t = 0; t < NT; t += 2) {
        TILE(t,     0, 1);
        TILE(t + 1, 1, 0);
    }

    // epilogue: C[row][col], row = m0 + qm*128 + wm*64 + mi*16 + lk8*4 + r,
    //                        col = n0 + qn*128 + wn*32 + nj*16 + lrow
    float bv[4];
#pragma unroll
    for (int nj2 = 0; nj2 < 4; ++nj2) {
        const int col = n0 + (nj2 >> 1) * 128 + wn * 32 + (nj2 & 1) * 16 + lrow;
        if constexpr (IS_FC1) {
            bv[nj2] = bias1[col];
        } else {
            bv[nj2] = (col < SHARED_F) ? bias1[col]
                                       : bias2[e * PART + col - SHARED_F];
        }
    }
#pragma unroll
    for (int mi2 = 0; mi2 < 8; ++mi2) {
        const int row0 = m0 + (mi2 >> 2) * 128 + wm * 64 + (mi2 & 3) * 16 + lk8 * 4;
#pragma unroll
        for (int nj2 = 0; nj2 < 4; ++nj2) {
            const int col = n0 + (nj2 >> 1) * 128 + wn * 32 + (nj2 & 1) * 16 + lrow;
            if constexpr (IS_FC1) {
                bf16* o = (bf16*)Outv;
#pragma unroll
                for (int r = 0; r < 4; ++r)
                    o[(size_t)(row0 + r) * LDOUT + col] =
                        (bf16)gelu_fast(acc[mi2][nj2][r] + bv[nj2]);
            } else {
                float* o = (float*)Outv;
#pragma unroll
                for (int r = 0; r < 4; ++r)
                    o[(size_t)(row0 + r) * LDOUT + col] =
                        acc[mi2][nj2][r] + bv[nj2];
            }
        }
    }
}

extern "C" void kernel_launch(void* const* d_in, const int* in_sizes, int n_in,
                              void* d_out, int out_size, void* d_ws, size_t ws_size,
                              hipStream_t stream) {
    const float* hidden = (const float*)d_in[0];
    const int*   idx    = (const int*)d_in[1];
    const float* W1     = (const float*)d_in[2];
    const float* b1     = (const float*)d_in[3];
    const float* W2     = (const float*)d_in[4];
    const float* b2     = (const float*)d_in[5];
    const float* We     = (const float*)d_in[6];
    const float* be     = (const float*)d_in[7];
    float* out = (float*)d_out;

    // workspace layout (bytes)
    char* ws = (char*)d_ws;
    bf16* hb   = (bf16*)(ws);                       //  50,331,648 B: [32768][768]
    bf16* h    = (bf16*)(ws + 50331648);            // 201,326,592 B: [32768][3072]
    bf16* W1t  = (bf16*)(ws + 251658240);           //   4,718,592 B: [3072][768]
    bf16* Wcat = (bf16*)(ws + 256376832);           //  28,311,552 B: [6][768][3072]
    // total 284,688,384 B

    // prep
    cvt_f32_bf16<<<4096, 256, 0, stream>>>(
        (const float4*)hidden, (bf16x4*)hb, (M_TOK * HIDDEN) / 4);
    transpose_cvt<<<dim3(HID_F / 32, HIDDEN / 32), 256, 0, stream>>>(
        W1, W1t, HIDDEN, HID_F);
    build_wcat<<<dim3(HIDDEN / 32, HID_F / 32, NEXP), 256, 0, stream>>>(
        W2, We, Wcat);

    // GEMM 1: [32768,768] x [768,3072] -> h (bf16, gelu fused)
    fc_8ph<true><<<(M_TOK / 256) * (HID_F / 256), 512, 0, stream>>>(
        hb, W1t, b1, nullptr, nullptr, h);

    // GEMM 2: [32768,3072] x [3072,768] -> out (fp32, bias fused, MoE select)
    fc_8ph<false><<<(M_TOK / 256) * (HIDDEN / 256), 512, 0, stream>>>(
        h, Wcat, b2, be, idx, out);
}

// Round 6
// 546.613 us; speedup vs baseline: 1.0691x; 1.0691x over previous
//
#include <hip/hip_runtime.h>
#include <hip/hip_bf16.h>
#include <cstdint>
#include <cstddef>

// Problem constants
#define HIDDEN   768
#define HID_F    3072
#define PART     192
#define SHARED_F 576
#define NEXP     6
#define BATCH    32
#define SEQ      1024
#define M_TOK    (BATCH * SEQ)   // 32768

typedef __bf16 bf16;
typedef __attribute__((ext_vector_type(8))) __bf16 bf16x8;
typedef __attribute__((ext_vector_type(4))) __bf16 bf16x4;
typedef __attribute__((ext_vector_type(4))) float  f32x4;

// ---- async global -> LDS copy, 16B per lane -----------------------------
__device__ __forceinline__ void gl2lds16(const void* g, void* l) {
    __builtin_amdgcn_global_load_lds(
        (const __attribute__((address_space(1))) void*)g,
        (__attribute__((address_space(3))) void*)l,
        16, 0, 0);
}

__device__ __forceinline__ f32x4 mfma16(bf16x8 a, bf16x8 b, f32x4 c) {
    return __builtin_amdgcn_mfma_f32_16x16x32_bf16(a, b, c, 0, 0, 0);
}

// compiler fence + raw barrier (no vmcnt/lgkm drain like __syncthreads)
#define CFENCE() asm volatile("" ::: "memory")
__device__ __forceinline__ void barrier_raw() {
    CFENCE();
    __builtin_amdgcn_s_barrier();
    CFENCE();
}

// Exact-GELU via Abramowitz-Stegun 7.1.26 rational erf (|eps| <= 1.5e-7).
__device__ __forceinline__ float gelu_fast(float x) {
    float xs = x * 0.70710678118654752f;       // x / sqrt(2)
    float ax = __builtin_fabsf(xs);
    float t  = __builtin_amdgcn_rcpf(1.0f + 0.3275911f * ax);
    float p  = t * (0.254829592f +
               t * (-0.284496736f +
               t * (1.421413741f +
               t * (-1.453152027f +
               t * 1.061405429f))));
    float e  = __expf(-xs * xs);
    float er = 1.0f - p * e;                   // erf(|xs|)
    er = (xs < 0.0f) ? -er : er;
    return 0.5f * x * (1.0f + er);
}

// ---- prep: fp32 -> bf16 vectorized convert ------------------------------
__global__ __launch_bounds__(256) void cvt_f32_bf16(
        const float4* __restrict__ src, bf16x4* __restrict__ dst, int n4) {
    int i      = blockIdx.x * 256 + threadIdx.x;
    int stride = gridDim.x * 256;
    for (; i < n4; i += stride) {
        float4 v = src[i];
        bf16x4 o = { (__bf16)v.x, (__bf16)v.y, (__bf16)v.z, (__bf16)v.w };
        dst[i] = o;
    }
}

// ---- prep: tiled transpose fp32[K][N] -> bf16[N][K] ---------------------
__global__ __launch_bounds__(256) void transpose_cvt(
        const float* __restrict__ src, bf16* __restrict__ dst, int K, int N) {
    __shared__ float t[32][33];
    const int n0 = blockIdx.x * 32, k0 = blockIdx.y * 32;
    const int tx = threadIdx.x & 31, ty = threadIdx.x >> 5;  // ty in 0..7
#pragma unroll
    for (int p = 0; p < 4; ++p) {
        int r = ty + p * 8;
        t[r][tx] = src[(size_t)(k0 + r) * N + n0 + tx];
    }
    __syncthreads();
#pragma unroll
    for (int p = 0; p < 4; ++p) {
        int rn = ty + p * 8;
        dst[(size_t)(n0 + rn) * K + k0 + tx] = (bf16)t[tx][rn];
    }
}

// ---- prep: Wcat[e][n][k] = (n<576 ? W2[k][n] : We[e][k][n-576]) as bf16 --
__global__ __launch_bounds__(256) void build_wcat(
        const float* __restrict__ W2, const float* __restrict__ We,
        bf16* __restrict__ Wcat) {
    __shared__ float t[32][33];
    const int e  = blockIdx.z;
    const int n0 = blockIdx.x * 32;
    const int k0 = blockIdx.y * 32;
    const int tx = threadIdx.x & 31, ty = threadIdx.x >> 5;
    const float* src;
    int ld, c;
    if (n0 < SHARED_F) { src = W2; ld = SHARED_F; c = n0 + tx; }
    else { src = We + (size_t)e * HID_F * PART; ld = PART; c = n0 + tx - SHARED_F; }
#pragma unroll
    for (int p = 0; p < 4; ++p) {
        int r = ty + p * 8;
        t[r][tx] = src[(size_t)(k0 + r) * ld + c];
    }
    __syncthreads();
    bf16* dst = Wcat + (size_t)e * HIDDEN * HID_F;
#pragma unroll
    for (int p = 0; p < 4; ++p) {
        int rn = ty + p * 8;
        dst[(size_t)(n0 + rn) * HID_F + k0 + tx] = (bf16)t[tx][rn];
    }
}

// ==========================================================================
// Shared staging/read/MFMA macros (R2 schedule, proven best: 2 barriers and
// 2 counted vmcnt per K-tile, register-pipelined cross-phase ds_reads).
// ==========================================================================

#define STAGE_A(kt, hm, bb) do {                                          \
    const bf16* g_ = gA + (size_t)((hm) * 128) * LDA + (kt) * 64;         \
    bf16* l_ = lA + ((bb) * 2 + (hm)) * 8192;                             \
    gl2lds16(g_, l_);                                                     \
    gl2lds16(g_ + (size_t)64 * LDA, l_ + 4096);                           \
} while (0)

#define STAGE_B(kt, hm, bb) do {                                          \
    const bf16* g_ = gB + (size_t)((hm) * 128) * LDB + (kt) * 64;         \
    bf16* l_ = lB + ((bb) * 2 + (hm)) * 8192;                             \
    gl2lds16(g_, l_);                                                     \
    gl2lds16(g_ + (size_t)64 * LDB, l_ + 4096);                           \
} while (0)

// fc2: B staged in 64-row thirds (one gl2lds = 8KB = one third)
#define STAGE_B3(kt, nj, bb)                                              \
    gl2lds16(gB + (size_t)((nj) * 64) * LDB + (kt) * 64,                  \
             lB + ((bb) * 3 + (nj)) * 4096)

#define RD_A(dst, qm, bb) do {                                            \
    const bf16* ab_ = fA + ((bb) * 2 + (qm)) * 8192;                      \
    _Pragma("unroll")                                                     \
    for (int mi = 0; mi < 4; ++mi) {                                      \
        dst[mi][0] = *(const bf16x8*)(ab_ + mi * 1024 + pca0);            \
        dst[mi][1] = *(const bf16x8*)(ab_ + mi * 1024 + pca1);            \
    }                                                                     \
} while (0)

#define RD_B(dst, qn, bb) do {                                            \
    const bf16* bb_ = fB + ((bb) * 2 + (qn)) * 8192;                      \
    _Pragma("unroll")                                                     \
    for (int nj = 0; nj < 2; ++nj) {                                      \
        dst[nj][0] = *(const bf16x8*)(bb_ + nj * 1024 + pcb0);            \
        dst[nj][1] = *(const bf16x8*)(bb_ + nj * 1024 + pcb1);            \
    }                                                                     \
} while (0)

// fc2: read one B frag (third nj) for this wave: row = nj*64 + wn*16 + lrow
#define RD_B3(dst, nj, bb) do {                                           \
    const bf16* b3_ = fB + ((bb) * 3 + (nj)) * 4096;                      \
    dst[0] = *(const bf16x8*)(b3_ + pcb0);                                \
    dst[1] = *(const bf16x8*)(b3_ + pcb1);                                \
} while (0)

#define MFMA16(A_, B_, qm, qn) do {                                       \
    __builtin_amdgcn_s_setprio(1);                                        \
    _Pragma("unroll")                                                     \
    for (int mi = 0; mi < 4; ++mi)                                        \
        _Pragma("unroll")                                                 \
        for (int nj = 0; nj < 2; ++nj) {                                  \
            acc[(qm)*4+mi][(qn)*2+nj] =                                   \
                mfma16(A_[mi][0], B_[nj][0], acc[(qm)*4+mi][(qn)*2+nj]);  \
            acc[(qm)*4+mi][(qn)*2+nj] =                                   \
                mfma16(A_[mi][1], B_[nj][1], acc[(qm)*4+mi][(qn)*2+nj]);  \
        }                                                                 \
    __builtin_amdgcn_s_setprio(0);                                        \
} while (0)

// fc2: 8-MFMA cluster: afr set x single B frag (third nj)
#define MFMA8(A_, B_, qm, nj) do {                                        \
    __builtin_amdgcn_s_setprio(1);                                        \
    _Pragma("unroll")                                                     \
    for (int mi = 0; mi < 4; ++mi) {                                      \
        acc[(qm)*4+mi][nj] =                                              \
            mfma16(A_[mi][0], B_[0], acc[(qm)*4+mi][nj]);                 \
        acc[(qm)*4+mi][nj] =                                              \
            mfma16(A_[mi][1], B_[1], acc[(qm)*4+mi][nj]);                 \
    }                                                                     \
    __builtin_amdgcn_s_setprio(0);                                        \
} while (0)

// ---- fc1 K-tile (R2, unchanged) -----------------------------------------
#define TILE(t, b, bo) do {                                               \
    const int tb1_ = ((t) + 1 < NT) ? (t) + 1 : (t) - 1;                  \
    const int ta2_ = ((t) + 2 < NT) ? (t) + 2 : (t);                      \
    /* -- phase 0: consume (afr0,bfr0); load bfr1(t); stage B1(t+1) -- */ \
    asm volatile("s_waitcnt vmcnt(4)" ::: "memory");                      \
    barrier_raw();                                                        \
    RD_B(bfr1, 1, b);                                                     \
    STAGE_B(tb1_, 1, bo);                                                 \
    MFMA16(afr0, bfr0, 0, 0);                                             \
    /* -- phase 1: consume (afr0,bfr1); load afr1(t); stage A1(t+1) -- */ \
    RD_A(afr1, 1, b);                                                     \
    STAGE_A(tb1_, 1, bo);                                                 \
    MFMA16(afr0, bfr1, 0, 1);                                             \
    /* -- phase 2: consume (afr1,bfr0); stage A0(t+2) ---------------- */ \
    STAGE_A(ta2_, 0, b);                                                  \
    MFMA16(afr1, bfr0, 1, 0);                                             \
    /* -- phase 3: consume (afr1,bfr1); load afr0/bfr0(t+1) from bo -- */ \
    asm volatile("s_waitcnt vmcnt(6)" ::: "memory");                      \
    barrier_raw();                                                        \
    RD_A(afr0, 0, bo);                                                    \
    RD_B(bfr0, 0, bo);                                                    \
    STAGE_B(ta2_, 0, b);                                                  \
    MFMA16(afr1, bfr1, 1, 1);                                             \
} while (0)

// ==========================================================================
// GEMM 1 (R2 winner, byte-identical schedule): 256x256, BK=64, 8 waves.
// ==========================================================================
__global__ __launch_bounds__(512, 2) void fc1_8ph(
        const bf16*  __restrict__ A,      // hb[32768][768]
        const bf16*  __restrict__ Bmat,   // W1t[3072][768]
        const float* __restrict__ bias1,  // b1[3072]
        bf16*        __restrict__ Out) {  // H[32768][3072]
    constexpr int LDA = HIDDEN, LDB = HIDDEN;
    constexpr int NT  = LDA / 64;          // 12
    constexpr int NTILE_N = HID_F / 256;   // 12
    constexpr int LDOUT   = HID_F;

    __shared__ alignas(16) bf16 Abuf[2 * 2 * 128 * 64];   // 64 KiB
    __shared__ alignas(16) bf16 Bbuf[2 * 2 * 128 * 64];   // 64 KiB

    const int tid  = threadIdx.x;
    const int wave = tid >> 6, lane = tid & 63;
    const int wm = wave >> 2, wn = wave & 3;              // 2M x 4N waves
    const int lrow = lane & 15, lk8 = (lane >> 4) & 3;

    const int L   = blockIdx.x;
    const int xcd = L & 7;
    const int j   = L >> 3;
    const int jm  = j / NTILE_N;
    const int mt  = xcd * 16 + jm;
    const int nt  = j - jm * NTILE_N;
    const int m0  = mt * 256;
    const int n0  = nt * 256;

    const int srow = tid >> 3;                       // 0..63
    const int lch  = (tid & 7) ^ (srow & 7);
    const bf16* gA = A    + (size_t)(m0 + srow) * LDA + lch * 8;
    const bf16* gB = Bmat + (size_t)(n0 + srow) * LDB + lch * 8;
    bf16* lA = Abuf + wave * 512;
    bf16* lB = Bbuf + wave * 512;

    const int rA = wm * 64 + lrow;
    const int rB = wn * 32 + lrow;
    const int pca0 = ((0 + lk8) ^ (rA & 7)) * 8;
    const int pca1 = ((4 + lk8) ^ (rA & 7)) * 8;
    const int pcb0 = ((0 + lk8) ^ (rB & 7)) * 8;
    const int pcb1 = ((4 + lk8) ^ (rB & 7)) * 8;
    const bf16* fA = Abuf + rA * 64;
    const bf16* fB = Bbuf + rB * 64;

    f32x4 acc[8][4] = {};
    bf16x8 afr0[4][2], afr1[4][2], bfr0[2][2], bfr1[2][2];

    STAGE_A(0, 0, 0); STAGE_B(0, 0, 0);
    STAGE_B(0, 1, 0); STAGE_A(0, 1, 0);
    STAGE_A(1, 0, 1); STAGE_B(1, 0, 1);
    asm volatile("s_waitcnt vmcnt(4)" ::: "memory");
    barrier_raw();
    RD_A(afr0, 0, 0);
    RD_B(bfr0, 0, 0);

#pragma unroll 1
    for (int t = 0; t < NT; t += 2) {
        TILE(t,     0, 1);
        TILE(t + 1, 1, 0);
    }

    float bv[4];
#pragma unroll
    for (int nj2 = 0; nj2 < 4; ++nj2) {
        const int col = n0 + (nj2 >> 1) * 128 + wn * 32 + (nj2 & 1) * 16 + lrow;
        bv[nj2] = bias1[col];
    }
#pragma unroll
    for (int mi2 = 0; mi2 < 8; ++mi2) {
        const int row0 = m0 + (mi2 >> 2) * 128 + wm * 64 + (mi2 & 3) * 16 + lk8 * 4;
#pragma unroll
        for (int nj2 = 0; nj2 < 4; ++nj2) {
            const int col = n0 + (nj2 >> 1) * 128 + wn * 32 + (nj2 & 1) * 16 + lrow;
#pragma unroll
            for (int r = 0; r < 4; ++r)
                Out[(size_t)(row0 + r) * LDOUT + col] =
                    (bf16)gelu_fast(acc[mi2][nj2][r] + bv[nj2]);
        }
    }
}

// ==========================================================================
// GEMM 2: 256x192 tile, BK=64, 8 waves (2M x 4N, per-wave 128x48).
// Grid = 128 mt x 4 nt = 512 blocks = EXACTLY 2 blocks/CU (was 384 = 1.5
// rounds -> 25% CU-idle).  Same per-CU sync-period count (96 tiles), each
// tile 48 MFMA/wave instead of 64 -> idle converted to useful work.
//
// Per-wave frag mapping: col = n0 + nj*64 + wn*16 + lrow  (nj = 0..2), so
// frag nj lives entirely in B-third nj (64 rows) -> staging thirds align
// with read sets and all overwrites keep >=1 barrier separation.
//
// Per tile t (R2 cadence, 7 vm-ops/tile):
//   p0: stage A1(t+1)->bo [2]; vmcnt(4); BAR; rd bfrC(t); q(afr0 x A,B)
//   p1: stage B2(t+1)->bo [1]; rd afr1(t);            q(afr0 x C)
//   p2: stage A0(t+2)->b  [2];                        q(afr1 x A,B)
//   p3: stage B0,B1(t+2)->b [2]; vmcnt(4); BAR;
//       rd afr0(t+1), bfrA(t+1), bfrB(t+1);           q(afr1 x C)
// FIFO sim: p0-wait retires A0(t+1); p3-wait retires B0B1(t+1), A1(t+1),
// B2(t+1) -> every read follows its guarantee barrier; youngest waited
// load is 2 phases (~1300cyc) old; never vmcnt(0).  Tail clamps stage
// targets to same-parity tiles (dead data, same slots).
// ==========================================================================
__global__ __launch_bounds__(512, 2) void fc2_moe192(
        const bf16*  __restrict__ A,      // H[32768][3072]
        const bf16*  __restrict__ Bmat,   // Wcat[6][768][3072]
        const float* __restrict__ b2,     // [576]
        const float* __restrict__ be,     // [6][192]
        const int*   __restrict__ idx,    // [32]
        float*       __restrict__ Out) {  // [32768][768]
    constexpr int LDA = HID_F, LDB = HID_F;
    constexpr int NT  = LDA / 64;          // 48
    constexpr int NTILE_N = HIDDEN / 192;  // 4
    constexpr int LDOUT   = HIDDEN;

    __shared__ alignas(16) bf16 Abuf[2 * 2 * 128 * 64];   // 64 KiB
    __shared__ alignas(16) bf16 Bbuf[2 * 3 * 64 * 64];    // 48 KiB

    const int tid  = threadIdx.x;
    const int wave = tid >> 6, lane = tid & 63;
    const int wm = wave >> 2, wn = wave & 3;              // 2M x 4N waves
    const int lrow = lane & 15, lk8 = (lane >> 4) & 3;

    const int L   = blockIdx.x;            // 0..511
    const int xcd = L & 7;
    const int j   = L >> 3;                // 0..63
    const int jm  = j >> 2;                // 0..15
    const int mt  = xcd * 16 + jm;         // 0..127
    const int nt  = j & 3;
    const int m0  = mt * 256;
    const int n0  = nt * 192;

    int e = idx[mt >> 2];                  // 4 m-tiles (256 rows) per batch elem
    e = e < 0 ? 0 : (e > NEXP - 1 ? NEXP - 1 : e);
    const bf16* Bt = Bmat + (size_t)e * HIDDEN * HID_F;

    const int srow = tid >> 3;                       // 0..63
    const int lch  = (tid & 7) ^ (srow & 7);
    const bf16* gA = A  + (size_t)(m0 + srow) * LDA + lch * 8;
    const bf16* gB = Bt + (size_t)(n0 + srow) * LDB + lch * 8;
    bf16* lA = Abuf + wave * 512;
    bf16* lB = Bbuf + wave * 512;

    const int rA  = wm * 64 + lrow;
    const int rBc = wn * 16 + lrow;                  // row within a third
    const int pca0 = ((0 + lk8) ^ (rA & 7)) * 8;
    const int pca1 = ((4 + lk8) ^ (rA & 7)) * 8;
    const int pcb0 = ((0 + lk8) ^ (rBc & 7)) * 8;
    const int pcb1 = ((4 + lk8) ^ (rBc & 7)) * 8;
    const bf16* fA = Abuf + rA * 64;
    const bf16* fB = Bbuf + rBc * 64;

    f32x4 acc[8][3] = {};
    bf16x8 afr0[4][2], afr1[4][2];
    bf16x8 bfrA[2], bfrB[2], bfrC[2];

    // prologue: tile0 [A0,B0,B1,B2,A1] (7 ops) + A0(1) [2] + B0B1(1) [2];
    // vmcnt(4) retires tile0's 7; queue entering loop = [A0(1)x2,B0B1(1)x2].
    STAGE_A(0, 0, 0);
    STAGE_B3(0, 0, 0); STAGE_B3(0, 1, 0); STAGE_B3(0, 2, 0);
    STAGE_A(0, 1, 0);
    STAGE_A(1, 0, 1);
    STAGE_B3(1, 0, 1); STAGE_B3(1, 1, 1);
    asm volatile("s_waitcnt vmcnt(4)" ::: "memory");
    barrier_raw();
    RD_A(afr0, 0, 0);
    RD_B3(bfrA, 0, 0);
    RD_B3(bfrB, 1, 0);

#pragma unroll 1
    for (int t = 0; t < NT; t += 2) {
#pragma unroll
        for (int u = 0; u < 2; ++u) {
            const int tt = t + u;
            const int b  = u, bo = u ^ 1;
            const int tp1 = (tt + 1 < NT) ? tt + 1 : tt - 1;
            const int tp2 = (tt + 2 < NT) ? tt + 2 : tt;
            // -- p0 --
            STAGE_A(tp1, 1, bo);
            asm volatile("s_waitcnt vmcnt(4)" ::: "memory");
            barrier_raw();
            RD_B3(bfrC, 2, b);
            MFMA8(afr0, bfrA, 0, 0);
            MFMA8(afr0, bfrB, 0, 1);
            // -- p1 --
            STAGE_B3(tp1, 2, bo);
            RD_A(afr1, 1, b);
            MFMA8(afr0, bfrC, 0, 2);
            // -- p2 --
            STAGE_A(tp2, 0, b);
            MFMA8(afr1, bfrA, 1, 0);
            MFMA8(afr1, bfrB, 1, 1);
            // -- p3 --
            STAGE_B3(tp2, 0, b); STAGE_B3(tp2, 1, b);
            asm volatile("s_waitcnt vmcnt(4)" ::: "memory");
            barrier_raw();
            RD_A(afr0, 0, bo);
            RD_B3(bfrA, 0, bo);
            RD_B3(bfrB, 1, bo);
            MFMA8(afr1, bfrC, 1, 2);
        }
    }

    // epilogue: row = m0 + qm*128 + wm*64 + mi*16 + lk8*4 + r,
    //           col = n0 + nj*64 + wn*16 + lrow
    float bv[3];
#pragma unroll
    for (int nj = 0; nj < 3; ++nj) {
        const int col = n0 + nj * 64 + wn * 16 + lrow;
        bv[nj] = (col < SHARED_F) ? b2[col] : be[e * PART + col - SHARED_F];
    }
#pragma unroll
    for (int mi2 = 0; mi2 < 8; ++mi2) {
        const int row0 = m0 + (mi2 >> 2) * 128 + wm * 64 + (mi2 & 3) * 16 + lk8 * 4;
#pragma unroll
        for (int nj = 0; nj < 3; ++nj) {
            const int col = n0 + nj * 64 + wn * 16 + lrow;
#pragma unroll
            for (int r = 0; r < 4; ++r)
                Out[(size_t)(row0 + r) * LDOUT + col] = acc[mi2][nj][r] + bv[nj];
        }
    }
}

extern "C" void kernel_launch(void* const* d_in, const int* in_sizes, int n_in,
                              void* d_out, int out_size, void* d_ws, size_t ws_size,
                              hipStream_t stream) {
    const float* hidden = (const float*)d_in[0];
    const int*   idx    = (const int*)d_in[1];
    const float* W1     = (const float*)d_in[2];
    const float* b1     = (const float*)d_in[3];
    const float* W2     = (const float*)d_in[4];
    const float* b2     = (const float*)d_in[5];
    const float* We     = (const float*)d_in[6];
    const float* be     = (const float*)d_in[7];
    float* out = (float*)d_out;

    // workspace layout (bytes)
    char* ws = (char*)d_ws;
    bf16* hb   = (bf16*)(ws);                       //  50,331,648 B: [32768][768]
    bf16* h    = (bf16*)(ws + 50331648);            // 201,326,592 B: [32768][3072]
    bf16* W1t  = (bf16*)(ws + 251658240);           //   4,718,592 B: [3072][768]
    bf16* Wcat = (bf16*)(ws + 256376832);           //  28,311,552 B: [6][768][3072]
    // total 284,688,384 B

    // prep
    cvt_f32_bf16<<<4096, 256, 0, stream>>>(
        (const float4*)hidden, (bf16x4*)hb, (M_TOK * HIDDEN) / 4);
    transpose_cvt<<<dim3(HID_F / 32, HIDDEN / 32), 256, 0, stream>>>(
        W1, W1t, HIDDEN, HID_F);
    build_wcat<<<dim3(HIDDEN / 32, HID_F / 32, NEXP), 256, 0, stream>>>(
        W2, We, Wcat);

    // GEMM 1: [32768,768] x [768,3072] -> h (bf16, gelu fused)
    fc1_8ph<<<(M_TOK / 256) * (HID_F / 256), 512, 0, stream>>>(
        hb, W1t, b1, h);

    // GEMM 2: [32768,3072] x [3072,768] -> out (fp32, bias fused, MoE select)
    // 256x192 tiles: grid 512 = exactly 2 blocks/CU (balanced, no idle round)
    fc2_moe192<<<(M_TOK / 256) * (HIDDEN / 192), 512, 0, stream>>>(
        h, Wcat, b2, be, idx, out);
}